// Round 6
// baseline (549.660 us; speedup 1.0000x reference)
//
#include <hip/hip_runtime.h>
#include <hip/hip_bf16.h>

typedef __bf16 bf16_t;
typedef __bf16 bf16x4_t __attribute__((ext_vector_type(4)));
typedef __bf16 bf16x8_t __attribute__((ext_vector_type(8)));
typedef float f32x4_t __attribute__((ext_vector_type(4)));
typedef float f32x16_t __attribute__((ext_vector_type(16)));

typedef __attribute__((address_space(1))) void gvoid_t;
typedef __attribute__((address_space(3))) void svoid_t;

__device__ __forceinline__ void gload_lds16(const void* g, void* s) {
    // async global->LDS, 16B per lane; LDS dest = wave-uniform base + lane*16
    __builtin_amdgcn_global_load_lds((gvoid_t*)g, (svoid_t*)s, 16, 0, 0);
}

// ---------------------------------------------------------------------------
// GEMM: C[M,N] = scale * (A[M,K] @ Bt[N,K]^T) + bias
// R8 = byte-identical revert to the proven R0 kernel (88.6us attn GEMMs,
// MfmaUtil 33%, 8 blocks/CU on the attn grids — occupancy hides all latency;
// every 256^2 deep-pipeline variant measured slower: 104/104/111us).
//
// 128x128 block tile, BK=32, 4 waves in 2x2, each wave 64x64 via a 2x2 grid
// of 32x32 accs using v_mfma_f32_32x32x16_bf16.
//
// LDS 16B-granule XOR swizzle: physical chunk col = logical ^ ((row>>1)&3),
// applied to the GLOBAL address on staging (global_load_lds forces slot =
// base + lane*16) and to the LDS offset on the read side.
//
// Tile swizzle: XCD-contiguous remap + bands of 8 by-rows walked col-major.
//
// STORE_T: write C transposed in per-batch segments (V -> V^T fused).
// ---------------------------------------------------------------------------
template <typename CT, bool BIAS, bool STORE_T = false>
__global__ __launch_bounds__(256, 2)
void gemm_bt(const bf16_t* __restrict__ A, const bf16_t* __restrict__ Bt,
             CT* __restrict__ C, const float* __restrict__ bias,
             int M, int N, int K, float scale,
             size_t sA, size_t sB, size_t sC, int tshift)
{
    __shared__ bf16_t As[128 * 32];
    __shared__ bf16_t Bs[128 * 32];

    // ---- tile swizzle -----------------------------------------------------
    const int nx = gridDim.x, ny = gridDim.y;
    const int nblk = nx * ny * (int)gridDim.z;
    int lin = blockIdx.x + nx * (blockIdx.y + ny * blockIdx.z);
    int tile = lin;
    if ((nblk & 7) == 0)                       // XCD-contiguous remap
        tile = (lin & 7) * (nblk >> 3) + (lin >> 3);
    const int per_z = nx * ny;
    const int bz = tile / per_z;
    int t = tile - bz * per_z;
    const int SB = 8;                          // band height (by-rows)
    const int band = t / (nx * SB);
    const int r = t - band * (nx * SB);
    const int h = min(SB, ny - band * SB);
    const int bx = r / h;
    const int by = band * SB + (r - bx * h);
    // -----------------------------------------------------------------------

    A  += (size_t)bz * sA;
    Bt += (size_t)bz * sB;
    C  += (size_t)bz * sC;

    const int tid  = threadIdx.x;
    const int wave = tid >> 6;
    const int lane = tid & 63;
    const int m0 = by * 128;
    const int n0 = bx * 128;

    // staging: slot granule c = tid + 256*j; row = c>>2; holds logical chunk
    // (c&3) ^ ((row>>1)&3)  [swizzle]
    const int c0 = tid, c1 = tid + 256;
    const int r0 = c0 >> 2, r1 = c1 >> 2;
    const int k0c = (((c0 & 3) ^ ((r0 >> 1) & 3))) * 8;
    const int k1c = (((c1 & 3) ^ ((r1 >> 1) & 3))) * 8;
    const bf16_t* ag0 = A  + (size_t)(m0 + r0) * K + k0c;
    const bf16_t* ag1 = A  + (size_t)(m0 + r1) * K + k1c;
    const bf16_t* bg0 = Bt + (size_t)(n0 + r0) * K + k0c;
    const bf16_t* bg1 = Bt + (size_t)(n0 + r1) * K + k1c;
    bf16_t* asb0 = As + (size_t)(wave * 64) * 8;        // + lane*16B implied
    bf16_t* asb1 = As + (size_t)(wave * 64 + 256) * 8;
    bf16_t* bsb0 = Bs + (size_t)(wave * 64) * 8;
    bf16_t* bsb1 = Bs + (size_t)(wave * 64 + 256) * 8;

    // 32x32x16 fragment addressing:
    //   A/B operand: m(or n) = lane&31, k = (lane>>5)*8 + j, j in [0,8)
    //   k-step kk in {0,1}: logical granule = 2*kk + (lane>>5)
    const int lr  = lane & 31;
    const int kh  = lane >> 5;
    const int swz = (lr >> 1) & 3;     // row-swizzle term (wm/mi*32 don't affect)
    const int wm = (wave >> 1) * 64;
    const int wn = (wave & 1) * 64;

    f32x16_t acc[2][2];
#pragma unroll
    for (int i = 0; i < 2; ++i)
#pragma unroll
        for (int j = 0; j < 2; ++j)
            acc[i][j] = (f32x16_t)(0.f);

    for (int kt = 0; kt < K; kt += 32) {
        gload_lds16(ag0, asb0);
        gload_lds16(ag1, asb1);
        gload_lds16(bg0, bsb0);
        gload_lds16(bg1, bsb1);
        ag0 += 32; ag1 += 32; bg0 += 32; bg1 += 32;
        __builtin_amdgcn_s_waitcnt(0);   // drain vmcnt before barrier
        __syncthreads();

        bf16x8_t af[2][2], bfr[2][2];
#pragma unroll
        for (int mi = 0; mi < 2; ++mi)
#pragma unroll
            for (int kk = 0; kk < 2; ++kk)
                af[mi][kk] = *(const bf16x8_t*)
                    &As[(wm + mi * 32 + lr) * 32 + ((2 * kk + kh) ^ swz) * 8];
#pragma unroll
        for (int nj = 0; nj < 2; ++nj)
#pragma unroll
            for (int kk = 0; kk < 2; ++kk)
                bfr[nj][kk] = *(const bf16x8_t*)
                    &Bs[(wn + nj * 32 + lr) * 32 + ((2 * kk + kh) ^ swz) * 8];
#pragma unroll
        for (int mi = 0; mi < 2; ++mi)
#pragma unroll
            for (int nj = 0; nj < 2; ++nj)
#pragma unroll
                for (int kk = 0; kk < 2; ++kk)
                    acc[mi][nj] = __builtin_amdgcn_mfma_f32_32x32x16_bf16(
                        af[mi][kk], bfr[nj][kk], acc[mi][nj], 0, 0, 0);
        __syncthreads();   // protect LDS before next stage
    }

    // 32x32 C/D layout: col = lane&31, row = (reg&3)+8*(reg>>2)+4*(lane>>5)
    // [m74/m101 verified]
#pragma unroll
    for (int nj = 0; nj < 2; ++nj) {
        const int col = n0 + wn + nj * 32 + lr;
        const float bv = BIAS ? bias[col] : 0.0f;
#pragma unroll
        for (int mi = 0; mi < 2; ++mi) {
            f32x16_t v = acc[mi][nj];
#pragma unroll
            for (int g = 0; g < 4; ++g) {
                const int row = m0 + wm + mi * 32 + 8 * g + 4 * kh;
                if constexpr (STORE_T) {
                    // transposed: 4 consecutive l's of one VT row -> bf16x4
                    const int b = row >> tshift;
                    const int l = row & ((1 << tshift) - 1);
                    bf16x4_t o;
#pragma unroll
                    for (int rr = 0; rr < 4; ++rr)
                        o[rr] = (bf16_t)(v[g * 4 + rr] * scale + bv);
                    *(bf16x4_t*)((bf16_t*)C + ((size_t)b * N << tshift) +
                                 ((size_t)col << tshift) + l) = o;
                } else {
#pragma unroll
                    for (int rr = 0; rr < 4; ++rr) {
                        float val = v[g * 4 + rr] * scale + bv;
                        C[(size_t)(row + rr) * N + col] = (CT)val;
                    }
                }
            }
        }
    }
}

// ---------------------------------------------------------------------------
// LayerNorm body: one wave per row, D = NV*256 (NV float4 per lane). fp32 in,
// bf16 out. (Device body so two modalities share ONE launch.)
// ---------------------------------------------------------------------------
template <int NV>
__device__ __forceinline__
void ln_body(const float* __restrict__ x, const float* __restrict__ g,
             const float* __restrict__ b, bf16_t* __restrict__ y)
{
    const int D = NV * 256;
    const int wave = threadIdx.x >> 6, lane = threadIdx.x & 63;
    const size_t row = (size_t)blockIdx.x * 4 + wave;
    const float4* xr = (const float4*)(x + row * D);

    float4 v[NV];
    float s = 0.f, sq = 0.f;
#pragma unroll
    for (int i = 0; i < NV; ++i) {
        v[i] = xr[lane + 64 * i];
        s  += v[i].x + v[i].y + v[i].z + v[i].w;
        sq += v[i].x * v[i].x + v[i].y * v[i].y + v[i].z * v[i].z + v[i].w * v[i].w;
    }
#pragma unroll
    for (int m = 32; m; m >>= 1) {
        s  += __shfl_xor(s, m, 64);
        sq += __shfl_xor(sq, m, 64);
    }
    const float mean = s / D;
    const float rstd = rsqrtf(fmaxf(sq / D - mean * mean, 0.f) + 1e-5f);

#pragma unroll
    for (int i = 0; i < NV; ++i) {
        const int c4 = lane + 64 * i;
        float4 gg = ((const float4*)g)[c4];
        float4 bb = ((const float4*)b)[c4];
        bf16x4_t o;
        o[0] = (bf16_t)((v[i].x - mean) * rstd * gg.x + bb.x);
        o[1] = (bf16_t)((v[i].y - mean) * rstd * gg.y + bb.y);
        o[2] = (bf16_t)((v[i].z - mean) * rstd * gg.z + bb.z);
        o[3] = (bf16_t)((v[i].w - mean) * rstd * gg.w + bb.w);
        *(bf16x4_t*)(y + row * D + (size_t)c4 * 4) = o;
    }
}

// Both layernorms in one launch: grid (B*L/4, 2); y=0 -> modality1 (D=1024),
// y=1 -> modality2 (D=768). Branch is block-uniform.
__global__ __launch_bounds__(256, 4)
void layernorm2(const float* __restrict__ m1, const float* __restrict__ g1,
                const float* __restrict__ b1, bf16_t* __restrict__ y1,
                const float* __restrict__ m2, const float* __restrict__ g2,
                const float* __restrict__ b2, bf16_t* __restrict__ y2)
{
    if (blockIdx.y == 0) ln_body<4>(m1, g1, b1, y1);
    else                 ln_body<3>(m2, g2, b2, y2);
}

// ---------------------------------------------------------------------------
// In-place row softmax over 2048 bf16 entries; one wave per row.
// ---------------------------------------------------------------------------
__global__ __launch_bounds__(256, 4)
void softmax_rows(bf16_t* __restrict__ a)
{
    const int wave = threadIdx.x >> 6, lane = threadIdx.x & 63;
    const size_t row = (size_t)blockIdx.x * 4 + wave;
    bf16_t* r = a + row * 2048;

    float v[32];
    float mx = -3.0e38f;
#pragma unroll
    for (int i = 0; i < 4; ++i) {
        bf16x8_t t = *(const bf16x8_t*)(r + (size_t)(lane + 64 * i) * 8);
#pragma unroll
        for (int j = 0; j < 8; ++j) {
            v[i * 8 + j] = (float)t[j];
            mx = fmaxf(mx, v[i * 8 + j]);
        }
    }
#pragma unroll
    for (int m = 32; m; m >>= 1) mx = fmaxf(mx, __shfl_xor(mx, m, 64));
    float s = 0.f;
#pragma unroll
    for (int i = 0; i < 32; ++i) { v[i] = __expf(v[i] - mx); s += v[i]; }
#pragma unroll
    for (int m = 32; m; m >>= 1) s += __shfl_xor(s, m, 64);
    const float rs = 1.0f / s;
#pragma unroll
    for (int i = 0; i < 4; ++i) {
        bf16x8_t t;
#pragma unroll
        for (int j = 0; j < 8; ++j) t[j] = (bf16_t)(v[i * 8 + j] * rs);
        *(bf16x8_t*)(r + (size_t)(lane + 64 * i) * 8) = t;
    }
}

// ---------------------------------------------------------------------------
// All 4 weight conversions (fp32 [K][N] -> bf16 [N][K]) in ONE launch.
// grid (32, 32, 4): z selects the weight; N = 1024 for all; blocks with
// k0 >= K exit (uniform, before any barrier).
// ---------------------------------------------------------------------------
__global__ __launch_bounds__(256, 4)
void wconvT4(const float* __restrict__ Wq, const float* __restrict__ Wk,
             const float* __restrict__ Wv, const float* __restrict__ Wo,
             bf16_t* __restrict__ WqT, bf16_t* __restrict__ WkT,
             bf16_t* __restrict__ WvT, bf16_t* __restrict__ WoT)
{
    const int N = 1024;
    const float* w; bf16_t* wt; int K;
    switch (blockIdx.z) {
        case 0:  w = Wq; wt = WqT; K = 1024; break;
        case 1:  w = Wk; wt = WkT; K = 768;  break;
        case 2:  w = Wv; wt = WvT; K = 768;  break;
        default: w = Wo; wt = WoT; K = 1024; break;
    }
    const int n0 = blockIdx.x * 32, k0 = blockIdx.y * 32;
    if (k0 >= K) return;                        // block-uniform exit

    __shared__ float s[32][33];
    const int tx = threadIdx.x, ty = threadIdx.y;   // block (32,8)
#pragma unroll
    for (int r = 0; r < 4; ++r)
        s[ty + r * 8][tx] = w[(size_t)(k0 + ty + r * 8) * N + n0 + tx];
    __syncthreads();
#pragma unroll
    for (int r = 0; r < 4; ++r)
        wt[(size_t)(n0 + ty + r * 8) * K + k0 + tx] = (bf16_t)s[tx][ty + r * 8];
}

// ---------------------------------------------------------------------------

extern "C" void kernel_launch(void* const* d_in, const int* in_sizes, int n_in,
                              void* d_out, int out_size, void* d_ws, size_t ws_size,
                              hipStream_t stream)
{
    const int B = 8, L1 = 2048, L2 = 2048, D1 = 1024, D2 = 768, E = 1024;
    const float scale = 0.03125f;  // E^-0.5
    const int tsh = 11;            // log2(L2)

    const float* m1   = (const float*)d_in[0];
    const float* m2   = (const float*)d_in[1];
    const float* ln1g = (const float*)d_in[2];
    const float* ln1b = (const float*)d_in[3];
    const float* ln2g = (const float*)d_in[4];
    const float* ln2b = (const float*)d_in[5];
    const float* Wq   = (const float*)d_in[6];
    const float* bq   = (const float*)d_in[7];
    const float* Wk   = (const float*)d_in[8];
    const float* bk   = (const float*)d_in[9];
    const float* Wv   = (const float*)d_in[10];
    const float* bv   = (const float*)d_in[11];
    const float* Wo   = (const float*)d_in[12];
    const float* bo   = (const float*)d_in[13];
    float* out = (float*)d_out;

    bf16_t* ws = (bf16_t*)d_ws;
    size_t off = 0;
    auto alloc = [&](size_t n) { bf16_t* p = ws + off; off += n; return p; };
    bf16_t* WqT = alloc((size_t)E * D1);
    bf16_t* WkT = alloc((size_t)E * D2);
    bf16_t* WvT = alloc((size_t)E * D2);
    bf16_t* WoT = alloc((size_t)D1 * E);
    bf16_t* x1  = alloc((size_t)B * L1 * D1);
    bf16_t* x2  = alloc((size_t)B * L2 * D2);
    bf16_t* Qb  = alloc((size_t)B * L1 * E);
    bf16_t* Kb  = alloc((size_t)B * L2 * E);
    bf16_t* VTb = alloc((size_t)B * E * L2);   // V^T, written directly by proj
    bf16_t* ctx = alloc((size_t)B * L1 * E);
    bf16_t* attn = ws + off;
    const bool batched = (off + (size_t)B * L1 * L2) * sizeof(bf16_t) <= ws_size;

    dim3 blk256(256);

    // 1. weights -> bf16 transposed (ONE launch for all four)
    wconvT4<<<dim3(32, 32, 4), dim3(32, 8), 0, stream>>>(
        Wq, Wk, Wv, Wo, WqT, WkT, WvT, WoT);

    // 2. both layernorms -> bf16 (ONE launch)
    layernorm2<<<dim3(B * L1 / 4, 2), blk256, 0, stream>>>(
        m1, ln1g, ln1b, x1, m2, ln2g, ln2b, x2);

    // 3. projections (V writes V^T directly via STORE_T epilogue)
    gemm_bt<bf16_t, true><<<dim3(E / 128, B * L1 / 128, 1), blk256, 0, stream>>>(
        x1, WqT, Qb, bq, B * L1, E, D1, 1.0f, 0, 0, 0, 0);
    gemm_bt<bf16_t, true><<<dim3(E / 128, B * L2 / 128, 1), blk256, 0, stream>>>(
        x2, WkT, Kb, bk, B * L2, E, D2, 1.0f, 0, 0, 0, 0);
    gemm_bt<bf16_t, true, true><<<dim3(E / 128, B * L2 / 128, 1), blk256, 0, stream>>>(
        x2, WvT, VTb, bv, B * L2, E, D2, 1.0f, 0, 0, 0, tsh);

    // 4. attention
    if (batched) {
        gemm_bt<bf16_t, false><<<dim3(L2 / 128, L1 / 128, B), blk256, 0, stream>>>(
            Qb, Kb, attn, nullptr, L1, L2, E, scale,
            (size_t)L1 * E, (size_t)L2 * E, (size_t)L1 * L2, 0);
        softmax_rows<<<dim3(B * L1 / 4), blk256, 0, stream>>>(attn);
        gemm_bt<bf16_t, false><<<dim3(E / 128, L1 / 128, B), blk256, 0, stream>>>(
            attn, VTb, ctx, nullptr, L1, E, L2, 1.0f,
            (size_t)L1 * L2, (size_t)E * L2, (size_t)L1 * E, 0);
    } else {
        for (int b = 0; b < B; ++b) {
            gemm_bt<bf16_t, false><<<dim3(L2 / 128, L1 / 128, 1), blk256, 0, stream>>>(
                Qb + (size_t)b * L1 * E, Kb + (size_t)b * L2 * E, attn, nullptr,
                L1, L2, E, scale, 0, 0, 0, 0);
            softmax_rows<<<dim3(L1 / 4), blk256, 0, stream>>>(attn);
            gemm_bt<bf16_t, false><<<dim3(E / 128, L1 / 128, 1), blk256, 0, stream>>>(
                attn, VTb + (size_t)b * E * L2, ctx + (size_t)b * L1 * E, nullptr,
                L1, E, L2, 1.0f, 0, 0, 0, 0);
        }
    }

    // 5. output projection -> fp32 d_out
    gemm_bt<float, true><<<dim3(D1 / 128, B * L1 / 128, 1), blk256, 0, stream>>>(
        ctx, WoT, out, bo, B * L1, D1, E, 1.0f, 0, 0, 0, 0);
}